// Round 1
// baseline (1745.189 us; speedup 1.0000x reference)
//
#include <hip/hip_runtime.h>
#include <math.h>

#define D_ 128
#define H_ 160
#define W_ 160
#define NVOX (D_*H_*W_)
#define HW (H_*W_)

// Gaussian kernel, sigma=1, radius=2, normalized (matches np.float32 computation well within threshold)
#define K0 0.40261996f
#define K1 0.24420134f
#define K2 0.05448868f

__device__ __forceinline__ float fetch_mov(const float* __restrict__ m, int d, int h, int w) {
    if ((unsigned)d >= (unsigned)D_ || (unsigned)h >= (unsigned)H_ || (unsigned)w >= (unsigned)W_) return 0.0f;
    return m[(d*H_ + h)*W_ + w];
}

// gradient of fixed image: jnp.gradient semantics (central interior, one-sided edges)
__global__ void grad_kernel(const float* __restrict__ f, float* __restrict__ g) {
    int i = blockIdx.x*blockDim.x + threadIdx.x;
    if (i >= NVOX) return;
    int w = i % W_;
    int h = (i / W_) % H_;
    int d = i / HW;
    float gd, gh, gw;
    if (d == 0)            gd = f[i + HW] - f[i];
    else if (d == D_-1)    gd = f[i] - f[i - HW];
    else                   gd = 0.5f*(f[i + HW] - f[i - HW]);
    if (h == 0)            gh = f[i + W_] - f[i];
    else if (h == H_-1)    gh = f[i] - f[i - W_];
    else                   gh = 0.5f*(f[i + W_] - f[i - W_]);
    if (w == 0)            gw = f[i + 1] - f[i];
    else if (w == W_-1)    gw = f[i] - f[i - 1];
    else                   gw = 0.5f*(f[i + 1] - f[i - 1]);
    g[i]         = gd;
    g[NVOX + i]  = gh;
    g[2*NVOX + i]= gw;
}

// trilinear warp: warped = mov sampled at (d,h,w) + vf, constant(0) OOB
__global__ void warp_kernel(const float* __restrict__ mov, const float* __restrict__ vf,
                            float* __restrict__ out) {
    int i = blockIdx.x*blockDim.x + threadIdx.x;
    if (i >= NVOX) return;
    int w = i % W_;
    int h = (i / W_) % H_;
    int d = i / HW;
    float cd = (float)d + vf[i];
    float ch = (float)h + vf[NVOX + i];
    float cw = (float)w + vf[2*NVOX + i];
    float fd0 = floorf(cd), fh0 = floorf(ch), fw0 = floorf(cw);
    int d0 = (int)fd0, h0 = (int)fh0, w0 = (int)fw0;
    float td = cd - fd0, th = ch - fh0, tw = cw - fw0;
    float c000 = fetch_mov(mov, d0,   h0,   w0  );
    float c001 = fetch_mov(mov, d0,   h0,   w0+1);
    float c010 = fetch_mov(mov, d0,   h0+1, w0  );
    float c011 = fetch_mov(mov, d0,   h0+1, w0+1);
    float c100 = fetch_mov(mov, d0+1, h0,   w0  );
    float c101 = fetch_mov(mov, d0+1, h0,   w0+1);
    float c110 = fetch_mov(mov, d0+1, h0+1, w0  );
    float c111 = fetch_mov(mov, d0+1, h0+1, w0+1);
    float c00 = c000 + tw*(c001 - c000);
    float c01 = c010 + tw*(c011 - c010);
    float c10 = c100 + tw*(c101 - c100);
    float c11 = c110 + tw*(c111 - c110);
    float c0 = c00 + th*(c01 - c00);
    float c1 = c10 + th*(c11 - c10);
    out[i] = c0 + td*(c1 - c0);
}

// demon force + vf update (in-place)
__global__ void force_kernel(const float* __restrict__ warped, const float* __restrict__ fix,
                             const float* __restrict__ gfix, float* __restrict__ vf) {
    int i = blockIdx.x*blockDim.x + threadIdx.x;
    if (i >= NVOX) return;
    int w = i % W_;
    int h = (i / W_) % H_;
    int d = i / HW;
    float gd, gh, gw;
    if (d == 0)            gd = warped[i + HW] - warped[i];
    else if (d == D_-1)    gd = warped[i] - warped[i - HW];
    else                   gd = 0.5f*(warped[i + HW] - warped[i - HW]);
    if (h == 0)            gh = warped[i + W_] - warped[i];
    else if (h == H_-1)    gh = warped[i] - warped[i - W_];
    else                   gh = 0.5f*(warped[i + W_] - warped[i - W_]);
    if (w == 0)            gw = warped[i + 1] - warped[i];
    else if (w == W_-1)    gw = warped[i] - warped[i - 1];
    else                   gw = 0.5f*(warped[i + 1] - warped[i - 1]);
    float diff = warped[i] - fix[i];
    float g0 = gd + gfix[i];
    float g1 = gh + gfix[NVOX + i];
    float g2 = gw + gfix[2*NVOX + i];
    float denom = g0*g0 + g1*g1 + g2*g2 + diff*diff;
    float scale = (denom > 1e-6f) ? (-diff/denom) : 0.0f;
    vf[i]          += scale*g0;
    vf[NVOX + i]   += scale*g1;
    vf[2*NVOX + i] += scale*g2;
}

// 5-tap Gaussian along one axis, zero padding ('SAME' conv), over all 3 channels
__global__ void smooth_kernel(const float* __restrict__ src, float* __restrict__ dst, int axis) {
    int i = blockIdx.x*blockDim.x + threadIdx.x;
    if (i >= 3*NVOX) return;
    int r = i % NVOX;
    int w = r % W_;
    int h = (r / W_) % H_;
    int d = r / HW;
    int p, S, stride;
    if (axis == 0)      { p = d; S = D_; stride = HW; }
    else if (axis == 1) { p = h; S = H_; stride = W_; }
    else                { p = w; S = W_; stride = 1; }
    float acc = K0 * src[i];
    if (p >= 1)     acc += K1 * src[i - stride];
    if (p >= 2)     acc += K2 * src[i - 2*stride];
    if (p <= S-2)   acc += K1 * src[i + stride];
    if (p <= S-3)   acc += K2 * src[i + 2*stride];
    dst[i] = acc;
}

extern "C" void kernel_launch(void* const* d_in, const int* in_sizes, int n_in,
                              void* d_out, int out_size, void* d_ws, size_t ws_size,
                              hipStream_t stream) {
    const float* mov = (const float*)d_in[0];
    const float* fix = (const float*)d_in[1];
    // iterations is fixed at 10 by setup_inputs
    const int ITERS = 10;

    float* ws     = (float*)d_ws;
    float* gfix   = ws;              // 3N
    float* vfA    = ws + 3*NVOX;     // 3N
    float* warped = ws + 6*NVOX;     // N
    float* vfB    = (float*)d_out;   // 3N — scratch during iterations, final copy at end

    const int nb1 = (NVOX + 255)/256;
    const int nb3 = (3*NVOX + 255)/256;

    grad_kernel<<<nb1, 256, 0, stream>>>(fix, gfix);
    hipMemsetAsync(vfA, 0, (size_t)3*NVOX*sizeof(float), stream);

    float* cur = vfA;
    float* alt = vfB;
    for (int it = 0; it < ITERS; ++it) {
        warp_kernel<<<nb1, 256, 0, stream>>>(mov, cur, warped);
        force_kernel<<<nb1, 256, 0, stream>>>(warped, fix, gfix, cur);
        smooth_kernel<<<nb3, 256, 0, stream>>>(cur, alt, 0);
        smooth_kernel<<<nb3, 256, 0, stream>>>(alt, cur, 1);
        smooth_kernel<<<nb3, 256, 0, stream>>>(cur, alt, 2);
        float* t = cur; cur = alt; alt = t;
    }
    // after an even number of swaps cur == vfA; copy result to d_out
    hipMemcpyAsync(d_out, cur, (size_t)3*NVOX*sizeof(float), hipMemcpyDeviceToDevice, stream);
}

// Round 2
// 1081.334 us; speedup vs baseline: 1.6139x; 1.6139x over previous
//
#include <hip/hip_runtime.h>
#include <math.h>

#define D_ 128
#define H_ 160
#define W_ 160
#define NVOX (D_*H_*W_)
#define HW (H_*W_)

// Gaussian kernel, sigma=1, radius=2, normalized
#define K0 0.40261996f
#define K1 0.24420134f
#define K2 0.05448868f

#define TS 32
#define CHUNK 16

__device__ __forceinline__ float fetch_mov(const float* __restrict__ m, int d, int h, int w) {
    if ((unsigned)d >= (unsigned)D_ || (unsigned)h >= (unsigned)H_ || (unsigned)w >= (unsigned)W_) return 0.0f;
    return m[(d*H_ + h)*W_ + w];
}

// gradient of fixed image: jnp.gradient semantics (central interior, one-sided edges)
__global__ void grad_kernel(const float* __restrict__ f, float* __restrict__ g) {
    int i = blockIdx.x*blockDim.x + threadIdx.x;
    if (i >= NVOX) return;
    int w = i % W_;
    int h = (i / W_) % H_;
    int d = i / HW;
    float gd, gh, gw;
    if (d == 0)            gd = f[i + HW] - f[i];
    else if (d == D_-1)    gd = f[i] - f[i - HW];
    else                   gd = 0.5f*(f[i + HW] - f[i - HW]);
    if (h == 0)            gh = f[i + W_] - f[i];
    else if (h == H_-1)    gh = f[i] - f[i - W_];
    else                   gh = 0.5f*(f[i + W_] - f[i - W_]);
    if (w == 0)            gw = f[i + 1] - f[i];
    else if (w == W_-1)    gw = f[i] - f[i - 1];
    else                   gw = 0.5f*(f[i + 1] - f[i - 1]);
    g[i]         = gd;
    g[NVOX + i]  = gh;
    g[2*NVOX + i]= gw;
}

// trilinear warp: warped = mov sampled at (d,h,w) + vf, constant(0) OOB
__global__ void warp_kernel(const float* __restrict__ mov, const float* __restrict__ vf,
                            float* __restrict__ out) {
    int i = blockIdx.x*blockDim.x + threadIdx.x;
    if (i >= NVOX) return;
    int w = i % W_;
    int h = (i / W_) % H_;
    int d = i / HW;
    float cd = (float)d + vf[i];
    float ch = (float)h + vf[NVOX + i];
    float cw = (float)w + vf[2*NVOX + i];
    float fd0 = floorf(cd), fh0 = floorf(ch), fw0 = floorf(cw);
    int d0 = (int)fd0, h0 = (int)fh0, w0 = (int)fw0;
    float td = cd - fd0, th = ch - fh0, tw = cw - fw0;
    float c000 = fetch_mov(mov, d0,   h0,   w0  );
    float c001 = fetch_mov(mov, d0,   h0,   w0+1);
    float c010 = fetch_mov(mov, d0,   h0+1, w0  );
    float c011 = fetch_mov(mov, d0,   h0+1, w0+1);
    float c100 = fetch_mov(mov, d0+1, h0,   w0  );
    float c101 = fetch_mov(mov, d0+1, h0,   w0+1);
    float c110 = fetch_mov(mov, d0+1, h0+1, w0  );
    float c111 = fetch_mov(mov, d0+1, h0+1, w0+1);
    float c00 = c000 + tw*(c001 - c000);
    float c01 = c010 + tw*(c011 - c010);
    float c10 = c100 + tw*(c101 - c100);
    float c11 = c110 + tw*(c111 - c110);
    float c0 = c00 + th*(c01 - c00);
    float c1 = c10 + th*(c11 - c10);
    out[i] = c0 + td*(c1 - c0);
}

// demon force + vf update (in-place)
__global__ void force_kernel(const float* __restrict__ warped, const float* __restrict__ fix,
                             const float* __restrict__ gfix, float* __restrict__ vf) {
    int i = blockIdx.x*blockDim.x + threadIdx.x;
    if (i >= NVOX) return;
    int w = i % W_;
    int h = (i / W_) % H_;
    int d = i / HW;
    float gd, gh, gw;
    if (d == 0)            gd = warped[i + HW] - warped[i];
    else if (d == D_-1)    gd = warped[i] - warped[i - HW];
    else                   gd = 0.5f*(warped[i + HW] - warped[i - HW]);
    if (h == 0)            gh = warped[i + W_] - warped[i];
    else if (h == H_-1)    gh = warped[i] - warped[i - W_];
    else                   gh = 0.5f*(warped[i + W_] - warped[i - W_]);
    if (w == 0)            gw = warped[i + 1] - warped[i];
    else if (w == W_-1)    gw = warped[i] - warped[i - 1];
    else                   gw = 0.5f*(warped[i + 1] - warped[i - 1]);
    float diff = warped[i] - fix[i];
    float g0 = gd + gfix[i];
    float g1 = gh + gfix[NVOX + i];
    float g2 = gw + gfix[2*NVOX + i];
    float denom = g0*g0 + g1*g1 + g2*g2 + diff*diff;
    float scale = (denom > 1e-6f) ? (-diff/denom) : 0.0f;
    vf[i]          += scale*g0;
    vf[NVOX + i]   += scale*g1;
    vf[2*NVOX + i] += scale*g2;
}

// Fused separable 3D Gaussian (W conv in LDS, H conv in LDS, D conv via rolling
// register window). One read + one write of the 3-channel field per smooth.
// Grid: (W_/TS, H_/TS, (D_/CHUNK)*3); block 32x32.
__global__ __launch_bounds__(1024) void smooth3d_kernel(const float* __restrict__ src,
                                                        float* __restrict__ dst) {
    __shared__ float raw[36][36];   // input slice + 2-halo in H and W
    __shared__ float s1[36][32];    // after W-conv (H halo kept)
    const int tx = threadIdx.x;     // W within tile
    const int ty = threadIdx.y;     // H within tile
    const int tid = ty*32 + tx;
    const int w0 = blockIdx.x * TS;
    const int h0 = blockIdx.y * TS;
    const int nchunk = D_ / CHUNK;
    const int c  = blockIdx.z / nchunk;
    const int d0 = (blockIdx.z % nchunk) * CHUNK;
    const float* s = src + (size_t)c * NVOX;
    float*       o = dst + (size_t)c * NVOX;

    float win0=0.f, win1=0.f, win2=0.f, win3=0.f, win4=0.f;

    for (int dd = d0-2; dd < d0+CHUNK+2; ++dd) {
        // stage (36x36) halo slice for plane dd (zero outside volume)
        if ((unsigned)dd < (unsigned)D_) {
            const float* sp = s + dd*HW;
            for (int idx = tid; idx < 36*36; idx += 1024) {
                int lh = idx / 36, lw = idx % 36;
                int gh = h0 - 2 + lh, gw = w0 - 2 + lw;
                float v = 0.0f;
                if ((unsigned)gh < (unsigned)H_ && (unsigned)gw < (unsigned)W_) v = sp[gh*W_ + gw];
                raw[lh][lw] = v;
            }
        } else {
            for (int idx = tid; idx < 36*36; idx += 1024) raw[idx/36][idx%36] = 0.0f;
        }
        __syncthreads();
        // conv along W: 36 rows x 32 cols
        for (int r = ty; r < 36; r += 32) {
            const float* rp = raw[r];
            s1[r][tx] = K2*(rp[tx] + rp[tx+4]) + K1*(rp[tx+1] + rp[tx+3]) + K0*rp[tx+2];
        }
        __syncthreads();
        // conv along H -> register
        float s2 = K2*(s1[ty][tx] + s1[ty+4][tx]) + K1*(s1[ty+1][tx] + s1[ty+3][tx]) + K0*s1[ty+2][tx];
        // rolling window for D conv
        win0 = win1; win1 = win2; win2 = win3; win3 = win4; win4 = s2;
        int od = dd - 2;
        if (od >= d0 && od < d0 + CHUNK) {
            float v = K2*(win0 + win4) + K1*(win1 + win3) + K0*win2;
            o[od*HW + (h0 + ty)*W_ + w0 + tx] = v;
        }
    }
}

extern "C" void kernel_launch(void* const* d_in, const int* in_sizes, int n_in,
                              void* d_out, int out_size, void* d_ws, size_t ws_size,
                              hipStream_t stream) {
    const float* mov = (const float*)d_in[0];
    const float* fix = (const float*)d_in[1];
    const int ITERS = 10;

    float* ws     = (float*)d_ws;
    float* gfix   = ws;              // 3N
    float* vfA    = ws + 3*NVOX;     // 3N
    float* warped = ws + 6*NVOX;     // N
    float* vfB    = (float*)d_out;   // 3N — scratch during iterations

    const int nb1 = (NVOX + 255)/256;

    grad_kernel<<<nb1, 256, 0, stream>>>(fix, gfix);
    hipMemsetAsync(vfA, 0, (size_t)3*NVOX*sizeof(float), stream);

    dim3 sg(W_/TS, H_/TS, (D_/CHUNK)*3);
    dim3 sb(32, 32);

    float* cur = vfA;
    float* alt = vfB;
    for (int it = 0; it < ITERS; ++it) {
        warp_kernel<<<nb1, 256, 0, stream>>>(mov, cur, warped);
        force_kernel<<<nb1, 256, 0, stream>>>(warped, fix, gfix, cur);
        smooth3d_kernel<<<sg, sb, 0, stream>>>(cur, alt);
        float* t = cur; cur = alt; alt = t;
    }
    // after an even number of swaps cur == vfA; copy result to d_out
    hipMemcpyAsync(d_out, cur, (size_t)3*NVOX*sizeof(float), hipMemcpyDeviceToDevice, stream);
}